// Round 7
// baseline (621.973 us; speedup 1.0000x reference)
//
#include <hip/hip_runtime.h>
#include <math.h>

// Problem constants
#define NPOS 65536   // B*H*W = 8*1*8192
#define NCH  128
#define DELTA 0.008f // argmax top-2 gap below which we recompute in exact fp32
#define HPAD 16      // ints per histogram bin slot (64 B = 1 cache line per bin)

// ws layout (float element offsets)
#define OFF_XR   0u                       // XRB bf16 [n][128] lives here
#define OFF_W1T  8388608u                 // fixup fp32 [cin][cout]
#define OFF_W2T  (OFF_W1T + 16384u)
#define OFF_W3T  (OFF_W2T + 16384u)
#define OFF_B1F  (OFF_W3T + 16384u)
#define OFF_BRF  (OFF_B1F + 128u)
#define OFF_B2F  (OFF_BRF + 128u)
#define OFF_B3F  (OFF_B2F + 128u)         // 132 (129 used)
#define OFF_BF16 (OFF_B3F + 132u)         // ushort region
#define OFF_INT  (OFF_BF16 + 329728u)     // int region (bf16 region = 659456 ushorts)

// ushort offsets inside bf16 region
#define UW1H 0u
#define UW1L 16384u
#define UWRH 32768u
#define UWRL 49152u
#define UW2H 65536u
#define UW2L 81920u
#define UW3H 98304u      // [144][128]; row128=mask, rows129..143=0
#define UW3L 116736u
#define UW2K 135168u     // cm2w bf16 transposed [k][out][ci] : 524288 -> end 659456

// frag-major LDS: [mg][kt][lane][8 ushorts], +32-ushort pad per mg
#define NST 2080         // 4*512 + 32

typedef short bf16x8 __attribute__((ext_vector_type(8)));
typedef float f32x4 __attribute__((ext_vector_type(4)));
#define MFMA16 __builtin_amdgcn_mfma_f32_16x16x32_bf16

__device__ __forceinline__ float lrelu(float v) { return v >= 0.0f ? v : 0.01f * v; }
__device__ __forceinline__ unsigned short f2bf(float f) {
    unsigned u = __float_as_uint(f);
    return (unsigned short)((u + 0x7fffu + ((u >> 16) & 1u)) >> 16);
}
__device__ __forceinline__ float bf2f(unsigned short h) {
    return __uint_as_float(((unsigned)h) << 16);
}
__device__ __forceinline__ unsigned long long pack4(unsigned short a, unsigned short b,
                                                    unsigned short c, unsigned short d) {
    return (unsigned long long)a | ((unsigned long long)b << 16)
         | ((unsigned long long)c << 32) | ((unsigned long long)d << 48);
}

// ---------------------------------------------------------------------------
// Manual grid barrier (R19). R18's cg::grid.sync() silently failed under the
// harness's stream capture (absmax=468 garbage: phase 1 read weights before
// phase 0 wrote them -> sync never happened). This one owns its state in ws:
// monotonic 2-level counters (32 groups x 32 blocks -> root -> gen), no
// resets -> no reset races. __threadfence() on gfx940+ emits the cross-XCD
// buffer_wbl2/buffer_inv, which is the device-scope fence G16 requires.
// Co-residency: grid 1024 = 256 CU x 4 blocks, bounds(256,4) + LDS 38,400B
// -> exactly 4 blocks/CU -> all blocks resident -> barrier cannot starve.
// ---------------------------------------------------------------------------
__device__ __forceinline__ void gridbar(int* cnt, int* root, int* gen, int bargen)
{
    __syncthreads();                 // block's stores complete (vmcnt0 before s_barrier)
    if (threadIdx.x == 0) {
        __threadfence();             // release: block's writes device-visible (wbl2)
        int grp = (int)(blockIdx.x & 31u);
        if (atomicAdd(&cnt[grp * HPAD], 1) == 32 * bargen - 1) {
            if (atomicAdd(root, 1) == 32 * bargen - 1) {
                __hip_atomic_store(gen, bargen, __ATOMIC_RELEASE,
                                   __HIP_MEMORY_SCOPE_AGENT);
            }
        }
        while (__hip_atomic_load(gen, __ATOMIC_ACQUIRE,
                                 __HIP_MEMORY_SCOPE_AGENT) < bargen)
            __builtin_amdgcn_s_sleep(8);
        __threadfence();             // acquire: invalidate L1/L2-stale before reads
    }
    __syncthreads();
}

// ---------------------------------------------------------------------------
// R19: ONE kernel, PLAIN launch, manual barriers. Phases are verbatim ports
// of the R17 kernels (bitwise-identical arithmetic):
//   P0 prep (blocks 0..255)  P1 fused (all 1024)  P2 fix (grid-stride)
//   P3 scatter (blocks 0..255)  P4 reg (grid-stride tiles)
// ---------------------------------------------------------------------------
__global__ __launch_bounds__(256, 4)
void k_mega(const float* __restrict__ X,
            const float* __restrict__ cl1_w, const float* __restrict__ cl1_b,
            const float* __restrict__ g1, const float* __restrict__ be1,
            const float* __restrict__ mu1, const float* __restrict__ va1,
            const float* __restrict__ cl2_w, const float* __restrict__ cl2_b,
            const float* __restrict__ cl3_w, const float* __restrict__ cl3_b,
            const float* __restrict__ reg1_w, const float* __restrict__ reg1_b,
            const float* __restrict__ gr, const float* __restrict__ ber,
            const float* __restrict__ mur, const float* __restrict__ var_,
            const float* __restrict__ cm2w, const float* __restrict__ cm2b,
            const float* __restrict__ cm3w, const float* __restrict__ cm3b,
            float* __restrict__ wsf, unsigned short* __restrict__ wbf,
            unsigned short* __restrict__ XRB, float* __restrict__ out_mask,
            int* __restrict__ inds, int* __restrict__ hist, int* __restrict__ cur,
            int* __restrict__ fixcnt, int* __restrict__ fixlist,
            int* __restrict__ bucket, float* __restrict__ out,
            int* __restrict__ bcnt, int* __restrict__ broot, int* __restrict__ bgen)
{
    __shared__ union __align__(16) SM {
        struct { float tl[32 * 132]; } prep;                       // 16,896 B
        struct {                                                   // 38,400 B
            unsigned short XBh[64 * 136];
            unsigned short XBl[64 * 136];
            float sm1[256]; float sm2[256]; int si1[256];
            int lh[128];
        } f;
        struct { float xw[4][128]; } x;                            //  2,048 B
        struct { int lh[128]; int gb[128]; int sv[128]; int sh[128]; } s;
        struct {                                                   // 18,440 B
            unsigned short XP[4 * NST];
            float red[64];
            int sh[128]; int sv[128]; int st[128]; int skj[2];
        } r;
    } U;

    const int t = threadIdx.x;
    const int bid0 = blockIdx.x;
    const int lane = t & 63;
    const int wv = __builtin_amdgcn_readfirstlane(t >> 6);

    // =================== Phase 0: prep ===================
    if (bid0 < 128) {
        if (t < 128) {
            const int cout = bid0;
            const int cin = t;
            const int row = cout * 128 + cin;
            float s1 = g1[cout] / sqrtf(va1[cout] + 1e-5f);
            float sr = gr[cout] / sqrtf(var_[cout] + 1e-5f);
            float w1 = cl1_w[row] * s1;
            float wr = reg1_w[row] * sr;
            float w2 = cl2_w[row];
            float w3 = cl3_w[row];
            wsf[OFF_W1T + cin * 128 + cout] = w1;
            wsf[OFF_W2T + cin * 128 + cout] = w2;
            wsf[OFF_W3T + cin * 128 + cout] = w3;
            unsigned short h;
            h = f2bf(w1); wbf[UW1H + row] = h; wbf[UW1L + row] = f2bf(w1 - bf2f(h));
            h = f2bf(wr); wbf[UWRH + row] = h; wbf[UWRL + row] = f2bf(wr - bf2f(h));
            h = f2bf(w2); wbf[UW2H + row] = h; wbf[UW2L + row] = f2bf(w2 - bf2f(h));
            h = f2bf(w3); wbf[UW3H + row] = h; wbf[UW3L + row] = f2bf(w3 - bf2f(h));
            if (bid0 < 16) {        // W3 rows 128..143: mask row then zeros
                float v = (bid0 == 0) ? cl3_w[128 * 128 + t] : 0.0f;
                int jj = (128 + bid0) * 128 + t;
                h = f2bf(v); wbf[UW3H + jj] = h; wbf[UW3L + jj] = f2bf(v - bf2f(h));
            }
            if (bid0 == 0) {
                float s1b = g1[t] / sqrtf(va1[t] + 1e-5f);
                float srb = gr[t] / sqrtf(var_[t] + 1e-5f);
                wsf[OFF_B1F + t] = cl1_b[t] * s1b + be1[t] - mu1[t] * s1b;
                wsf[OFF_BRF + t] = reg1_b[t] * srb + ber[t] - mur[t] * srb;
                wsf[OFF_B2F + t] = cl2_b[t];
                wsf[OFF_B3F + t] = cl3_b[t];
                hist[t * HPAD] = 0;
                cur[t * HPAD] = 0;
            }
            if (bid0 == 1 && t == 0) { wsf[OFF_B3F + 128] = cl3_b[128]; fixcnt[0] = 0; }
        }
    } else if (bid0 < 256) {                 // cm2w transpose, one k per block
        int k = bid0 - 128;
        if (t < 128) {
            #pragma unroll
            for (int i = 0; i < 32; ++i) {
                float v = cm2w[(unsigned)k * 4096u + i * 128 + t];
                int ci = i * 4 + (t >> 5), o = t & 31;
                U.prep.tl[o * 132 + ci] = v;
            }
        }
        __syncthreads();
        if (t < 128) {
            #pragma unroll
            for (int i = 0; i < 32; ++i)
                wbf[UW2K + (unsigned)k * 4096u + i * 128 + t] = f2bf(U.prep.tl[i * 132 + t]);
        }
    }
    gridbar(bcnt, broot, bgen, 1);

    // =================== Phase 1: fused MFMA pipeline ===================
    {
        auto& XBh = U.f.XBh;  auto& XBl = U.f.XBl;
        auto& sm1 = U.f.sm1;  auto& sm2 = U.f.sm2;  auto& si1 = U.f.si1;
        auto& lh  = U.f.lh;

        const int cl16 = lane & 15;
        const int q8 = (lane >> 4) * 8;
        const int q4 = (lane >> 4) * 4;
        const unsigned nt64 = bid0 * 64u;
        const unsigned base = nt64 + (nt64 >> 13) * 1040384u;   // b*1048576 + w0

        const unsigned short* W1H = wbf + UW1H; const unsigned short* W1L = wbf + UW1L;
        const unsigned short* WRH = wbf + UWRH; const unsigned short* WRL = wbf + UWRL;
        const unsigned short* W2H = wbf + UW2H; const unsigned short* W2L = wbf + UW2L;
        const unsigned short* W3H = wbf + UW3H; const unsigned short* W3L = wbf + UW3L;
        const float* b1f = wsf + OFF_B1F;
        const float* brf = wsf + OFF_BRF;
        const float* b2f = wsf + OFF_B2F;
        const float* b3f = wsf + OFF_B3F;

        const f32x4 vzero = {0.f, 0.f, 0.f, 0.f};

        // ---- stage x tile -> bf16 hi/lo planes [pos][cin] ----
        {
            const int pos = t & 63, cig = t >> 6;
            #pragma unroll
            for (int l = 0; l < 8; ++l) {
                int ci0 = cig * 32 + l * 4;
                float v0 = X[base + (unsigned)(ci0 + 0) * 8192u + pos];
                float v1 = X[base + (unsigned)(ci0 + 1) * 8192u + pos];
                float v2 = X[base + (unsigned)(ci0 + 2) * 8192u + pos];
                float v3 = X[base + (unsigned)(ci0 + 3) * 8192u + pos];
                unsigned short h0 = f2bf(v0), h1 = f2bf(v1), h2 = f2bf(v2), h3 = f2bf(v3);
                unsigned long long ph = pack4(h0, h1, h2, h3);
                unsigned long long pl = pack4(f2bf(v0 - bf2f(h0)), f2bf(v1 - bf2f(h1)),
                                              f2bf(v2 - bf2f(h2)), f2bf(v3 - bf2f(h3)));
                *(unsigned long long*)&XBh[pos * 136 + ci0] = ph;
                *(unsigned long long*)&XBl[pos * 136 + ci0] = pl;
            }
        }
        __syncthreads();

        f32x4 acc[2][4];

        // ---- P1a: xr = lrelu(WR x + br) ----
        #pragma unroll
        for (int m = 0; m < 2; ++m)
            #pragma unroll
            for (int n = 0; n < 4; ++n) acc[m][n] = vzero;
        #pragma unroll
        for (int kt = 0; kt < 4; ++kt) {
            bf16x8 Bh[4], Bl[4];
            #pragma unroll
            for (int n = 0; n < 4; ++n) {
                int bo = (n * 16 + cl16) * 136 + kt * 32 + q8;
                Bh[n] = *(const bf16x8*)&XBh[bo];
                Bl[n] = *(const bf16x8*)&XBl[bo];
            }
            #pragma unroll
            for (int m = 0; m < 2; ++m) {
                int ao = (wv * 32 + m * 16 + cl16) * 128 + kt * 32 + q8;
                bf16x8 arh = *(const bf16x8*)&WRH[ao], arl = *(const bf16x8*)&WRL[ao];
                #pragma unroll
                for (int n = 0; n < 4; ++n) {
                    acc[m][n] = MFMA16(arh, Bl[n], acc[m][n], 0, 0, 0);
                    acc[m][n] = MFMA16(arl, Bh[n], acc[m][n], 0, 0, 0);
                    acc[m][n] = MFMA16(arh, Bh[n], acc[m][n], 0, 0, 0);
                }
            }
        }
        // xr epilogue -> global XRB
        {
            #pragma unroll
            for (int m = 0; m < 2; ++m) {
                int cb = wv * 32 + m * 16 + q4;
                float br0 = brf[cb], br1 = brf[cb + 1], br2 = brf[cb + 2], br3 = brf[cb + 3];
                #pragma unroll
                for (int n = 0; n < 4; ++n) {
                    unsigned pb = (nt64 + n * 16 + cl16) * 128u + cb;
                    ushort4 xo;
                    xo.x = f2bf(lrelu(acc[m][n][0] + br0));
                    xo.y = f2bf(lrelu(acc[m][n][1] + br1));
                    xo.z = f2bf(lrelu(acc[m][n][2] + br2));
                    xo.w = f2bf(lrelu(acc[m][n][3] + br3));
                    *(ushort4*)&XRB[pb] = xo;
                }
            }
        }

        // ---- P1b: y1 = lrelu(W1 x + b1) ----
        #pragma unroll
        for (int m = 0; m < 2; ++m)
            #pragma unroll
            for (int n = 0; n < 4; ++n) acc[m][n] = vzero;
        #pragma unroll
        for (int kt = 0; kt < 4; ++kt) {
            bf16x8 Bh[4], Bl[4];
            #pragma unroll
            for (int n = 0; n < 4; ++n) {
                int bo = (n * 16 + cl16) * 136 + kt * 32 + q8;
                Bh[n] = *(const bf16x8*)&XBh[bo];
                Bl[n] = *(const bf16x8*)&XBl[bo];
            }
            #pragma unroll
            for (int m = 0; m < 2; ++m) {
                int ao = (wv * 32 + m * 16 + cl16) * 128 + kt * 32 + q8;
                bf16x8 a1h = *(const bf16x8*)&W1H[ao], a1l = *(const bf16x8*)&W1L[ao];
                #pragma unroll
                for (int n = 0; n < 4; ++n) {
                    acc[m][n] = MFMA16(a1h, Bl[n], acc[m][n], 0, 0, 0);
                    acc[m][n] = MFMA16(a1l, Bh[n], acc[m][n], 0, 0, 0);
                    acc[m][n] = MFMA16(a1h, Bh[n], acc[m][n], 0, 0, 0);
                }
            }
        }
        __syncthreads();
        // y1 epilogue -> XB planes
        {
            #pragma unroll
            for (int m = 0; m < 2; ++m) {
                int cb = wv * 32 + m * 16 + q4;
                float b0 = b1f[cb], b1 = b1f[cb + 1], b2 = b1f[cb + 2], b3 = b1f[cb + 3];
                #pragma unroll
                for (int n = 0; n < 4; ++n) {
                    float v0 = lrelu(acc[m][n][0] + b0), v1 = lrelu(acc[m][n][1] + b1);
                    float v2 = lrelu(acc[m][n][2] + b2), v3 = lrelu(acc[m][n][3] + b3);
                    unsigned short h0 = f2bf(v0), h1 = f2bf(v1), h2 = f2bf(v2), h3 = f2bf(v3);
                    unsigned long long ph = pack4(h0, h1, h2, h3);
                    unsigned long long pl = pack4(f2bf(v0 - bf2f(h0)), f2bf(v1 - bf2f(h1)),
                                                  f2bf(v2 - bf2f(h2)), f2bf(v3 - bf2f(h3)));
                    int idx = (n * 16 + cl16) * 136 + cb;
                    *(unsigned long long*)&XBh[idx] = ph;
                    *(unsigned long long*)&XBl[idx] = pl;
                }
            }
        }
        __syncthreads();

        // ---- P2: y2 = lrelu(W2 y1 + b2) ----
        #pragma unroll
        for (int m = 0; m < 2; ++m)
            #pragma unroll
            for (int n = 0; n < 4; ++n) acc[m][n] = vzero;
        #pragma unroll
        for (int kt = 0; kt < 4; ++kt) {
            bf16x8 Bh[4], Bl[4];
            #pragma unroll
            for (int n = 0; n < 4; ++n) {
                int bo = (n * 16 + cl16) * 136 + kt * 32 + q8;
                Bh[n] = *(const bf16x8*)&XBh[bo];
                Bl[n] = *(const bf16x8*)&XBl[bo];
            }
            #pragma unroll
            for (int m = 0; m < 2; ++m) {
                int ao = (wv * 32 + m * 16 + cl16) * 128 + kt * 32 + q8;
                bf16x8 ah = *(const bf16x8*)&W2H[ao], al = *(const bf16x8*)&W2L[ao];
                #pragma unroll
                for (int n = 0; n < 4; ++n) {
                    acc[m][n] = MFMA16(ah, Bl[n], acc[m][n], 0, 0, 0);
                    acc[m][n] = MFMA16(al, Bh[n], acc[m][n], 0, 0, 0);
                    acc[m][n] = MFMA16(ah, Bh[n], acc[m][n], 0, 0, 0);
                }
            }
        }
        __syncthreads();
        {
            #pragma unroll
            for (int m = 0; m < 2; ++m) {
                int cb = wv * 32 + m * 16 + q4;
                float b0 = b2f[cb], b1 = b2f[cb + 1], b2 = b2f[cb + 2], b3 = b2f[cb + 3];
                #pragma unroll
                for (int n = 0; n < 4; ++n) {
                    float v0 = lrelu(acc[m][n][0] + b0), v1 = lrelu(acc[m][n][1] + b1);
                    float v2 = lrelu(acc[m][n][2] + b2), v3 = lrelu(acc[m][n][3] + b3);
                    unsigned short h0 = f2bf(v0), h1 = f2bf(v1), h2 = f2bf(v2), h3 = f2bf(v3);
                    unsigned long long ph = pack4(h0, h1, h2, h3);
                    unsigned long long pl = pack4(f2bf(v0 - bf2f(h0)), f2bf(v1 - bf2f(h1)),
                                                  f2bf(v2 - bf2f(h2)), f2bf(v3 - bf2f(h3)));
                    int idx = (n * 16 + cl16) * 136 + cb;
                    *(unsigned long long*)&XBh[idx] = ph;
                    *(unsigned long long*)&XBl[idx] = pl;
                }
            }
        }
        __syncthreads();

        // ---- P3: logits + mask row ----
        f32x4 accM = vzero;
        #pragma unroll
        for (int m = 0; m < 2; ++m)
            #pragma unroll
            for (int n = 0; n < 4; ++n) acc[m][n] = vzero;
        #pragma unroll
        for (int kt = 0; kt < 4; ++kt) {
            bf16x8 Bh[4], Bl[4];
            #pragma unroll
            for (int n = 0; n < 4; ++n) {
                int bo = (n * 16 + cl16) * 136 + kt * 32 + q8;
                Bh[n] = *(const bf16x8*)&XBh[bo];
                Bl[n] = *(const bf16x8*)&XBl[bo];
            }
            #pragma unroll
            for (int m = 0; m < 2; ++m) {
                int ao = (wv * 32 + m * 16 + cl16) * 128 + kt * 32 + q8;
                bf16x8 ah = *(const bf16x8*)&W3H[ao], al = *(const bf16x8*)&W3L[ao];
                #pragma unroll
                for (int n = 0; n < 4; ++n) {
                    acc[m][n] = MFMA16(ah, Bl[n], acc[m][n], 0, 0, 0);
                    acc[m][n] = MFMA16(al, Bh[n], acc[m][n], 0, 0, 0);
                    acc[m][n] = MFMA16(ah, Bh[n], acc[m][n], 0, 0, 0);
                }
            }
            {   // mask row; B-frag re-read from LDS at wave-uniform runtime addr
                int boM = (wv * 16 + cl16) * 136 + kt * 32 + q8;
                bf16x8 BhM = *(const bf16x8*)&XBh[boM];
                bf16x8 BlM = *(const bf16x8*)&XBl[boM];
                int ao = (128 + cl16) * 128 + kt * 32 + q8;
                bf16x8 ah = *(const bf16x8*)&W3H[ao], al = *(const bf16x8*)&W3L[ao];
                accM = MFMA16(ah, BlM, accM, 0, 0, 0);
                accM = MFMA16(al, BhM, accM, 0, 0, 0);
                accM = MFMA16(ah, BhM, accM, 0, 0, 0);
            }
        }

        // per-lane top-2, reduce, provisional hist, fix flags
        {
            float bb[2][4];
            #pragma unroll
            for (int m = 0; m < 2; ++m) {
                int cb = wv * 32 + m * 16 + q4;
                bb[m][0] = b3f[cb]; bb[m][1] = b3f[cb + 1];
                bb[m][2] = b3f[cb + 2]; bb[m][3] = b3f[cb + 3];
            }
            float m1[4], m2[4]; int i1[4];
            #pragma unroll
            for (int n = 0; n < 4; ++n) {
                m1[n] = -1e30f; m2[n] = -1e30f; i1[n] = 0;
                #pragma unroll
                for (int m = 0; m < 2; ++m) {
                    int cb = wv * 32 + m * 16 + q4;
                    #pragma unroll
                    for (int r = 0; r < 4; ++r) {
                        float v = acc[m][n][r] + bb[m][r];
                        if (v > m1[n]) { m2[n] = m1[n]; m1[n] = v; i1[n] = cb + r; }
                        else if (v > m2[n]) m2[n] = v;
                    }
                }
            }
            #pragma unroll
            for (int off = 16; off <= 32; off <<= 1) {
                #pragma unroll
                for (int n = 0; n < 4; ++n) {
                    float om1 = __shfl_xor(m1[n], off);
                    float om2 = __shfl_xor(m2[n], off);
                    int   oi1 = __shfl_xor(i1[n], off);
                    if (om1 > m1[n] || (om1 == m1[n] && oi1 < i1[n])) {
                        m2[n] = fmaxf(m1[n], om2); m1[n] = om1; i1[n] = oi1;
                    } else {
                        m2[n] = fmaxf(m2[n], om1);
                    }
                }
            }
            if ((lane >> 4) == 0) {
                #pragma unroll
                for (int n = 0; n < 4; ++n) {
                    sm1[wv * 64 + n * 16 + cl16] = m1[n];
                    sm2[wv * 64 + n * 16 + cl16] = m2[n];
                    si1[wv * 64 + n * 16 + cl16] = i1[n];
                }
            }
        }
        if ((lane >> 4) == 0) {
            float mb = b3f[128];
            out_mask[nt64 + wv * 16 + cl16] = lrelu(accM[0] + mb);
        }
        if (t < 128) lh[t] = 0;
        __syncthreads();
        if (t < 64) {
            float m1 = sm1[t], m2 = sm2[t];
            int i1 = si1[t];
            #pragma unroll
            for (int w = 1; w < 4; ++w) {
                float v1 = sm1[w * 64 + t];
                float v2 = sm2[w * 64 + t];
                int   vi = si1[w * 64 + t];
                if (v1 > m1) { m2 = fmaxf(m1, v2); m1 = v1; i1 = vi; }
                else         { m2 = fmaxf(m2, v1); }
            }
            int n = nt64 + t;
            inds[n] = i1;
            atomicAdd(&lh[i1], 1);
            if (m1 - m2 < DELTA) {
                int slot = atomicAdd(fixcnt, 1);
                fixlist[slot] = n;
            }
        }
        __syncthreads();
        if (t < 128 && lh[t] > 0) atomicAdd(&hist[t * HPAD], lh[t]);
    }
    gridbar(bcnt, broot, bgen, 2);

    // =================== Phase 2: exact-fp32 fixup (grid-stride) ===========
    {
        const int cnt = fixcnt[0];
        const float* W1T = wsf + OFF_W1T;
        const float* W2T = wsf + OFF_W2T;
        const float* W3T = wsf + OFF_W3T;
        const float* b1f = wsf + OFF_B1F;
        const float* b2f = wsf + OFF_B2F;
        const float* b3f = wsf + OFF_B3F;

        for (int idx = bid0 * 4 + wv; idx < cnt; idx += 4096) {
            int n = fixlist[idx];
            int oldid = inds[n];
            const float* xb = X + (unsigned)(n >> 13) * 1048576u + (unsigned)(n & 8191);
            float x0 = xb[(unsigned)lane * 8192u];
            float x1 = xb[(unsigned)(64 + lane) * 8192u];
            float a0, a1;

            U.x.xw[wv][lane] = x0; U.x.xw[wv][64 + lane] = x1;
            a0 = 0.f; a1 = 0.f;
            #pragma unroll 16
            for (int ci = 0; ci < 128; ++ci) {
                float xv = U.x.xw[wv][ci];
                const float* wr = W1T + ci * 128;
                a0 = fmaf(wr[lane], xv, a0);
                a1 = fmaf(wr[64 + lane], xv, a1);
            }
            x0 = lrelu(a0 + b1f[lane]); x1 = lrelu(a1 + b1f[64 + lane]);

            U.x.xw[wv][lane] = x0; U.x.xw[wv][64 + lane] = x1;
            a0 = 0.f; a1 = 0.f;
            #pragma unroll 16
            for (int ci = 0; ci < 128; ++ci) {
                float xv = U.x.xw[wv][ci];
                const float* wr = W2T + ci * 128;
                a0 = fmaf(wr[lane], xv, a0);
                a1 = fmaf(wr[64 + lane], xv, a1);
            }
            x0 = lrelu(a0 + b2f[lane]); x1 = lrelu(a1 + b2f[64 + lane]);

            U.x.xw[wv][lane] = x0; U.x.xw[wv][64 + lane] = x1;
            a0 = 0.f; a1 = 0.f;
            #pragma unroll 16
            for (int ci = 0; ci < 128; ++ci) {
                float xv = U.x.xw[wv][ci];
                const float* wr = W3T + ci * 128;
                a0 = fmaf(wr[lane], xv, a0);
                a1 = fmaf(wr[64 + lane], xv, a1);
            }
            float L0 = a0 + b3f[lane], L1 = a1 + b3f[64 + lane];
            float v; int id;
            if (L0 >= L1) { v = L0; id = lane; } else { v = L1; id = 64 + lane; }
            #pragma unroll
            for (int off = 1; off < 64; off <<= 1) {
                float ov = __shfl_xor(v, off);
                int   oi = __shfl_xor(id, off);
                if (ov > v || (ov == v && oi < id)) { v = ov; id = oi; }
            }
            if (lane == 0 && id != oldid) {
                inds[n] = id;
                atomicSub(&hist[oldid * HPAD], 1);
                atomicAdd(&hist[id * HPAD], 1);
            }
        }
    }
    gridbar(bcnt, broot, bgen, 3);

    // =================== Phase 3: scatter (blocks 0..255) ==================
    if (bid0 < 256) {
        if (t < 128) { int h = hist[t * HPAD]; U.s.sh[t] = h; U.s.sv[t] = h; U.s.lh[t] = 0; }
        __syncthreads();
        for (int d = 1; d < 128; d <<= 1) {
            int a = (t < 128 && t >= d) ? U.s.sv[t - d] : 0;
            __syncthreads();
            if (t < 128) U.s.sv[t] += a;
            __syncthreads();
        }
        int n = bid0 * 256 + t;
        int id = inds[n];
        int r = atomicAdd(&U.s.lh[id], 1);
        __syncthreads();
        if (t < 128 && U.s.lh[t] > 0)
            U.s.gb[t] = (U.s.sv[t] - U.s.sh[t]) + atomicAdd(&cur[t * HPAD], U.s.lh[t]);
        __syncthreads();
        bucket[U.s.gb[id] + r] = n;
    }
    gridbar(bcnt, broot, bgen, 4);

    // =================== Phase 4: bucketed reg MLP (grid-stride tiles) =====
    {
        auto& XP = U.r.XP;  auto& red = U.r.red;
        if (t < 128) {
            int h = hist[t * HPAD];
            U.r.sh[t] = h; U.r.sv[t] = h; U.r.st[t] = (h + 63) >> 6;
        }
        __syncthreads();
        for (int d = 1; d < 128; d <<= 1) {
            int a = (t < 128 && t >= d) ? U.r.sv[t - d] : 0;
            int b = (t < 128 && t >= d) ? U.r.st[t - d] : 0;
            __syncthreads();
            if (t < 128) { U.r.sv[t] += a; U.r.st[t] += b; }
            __syncthreads();
        }
        const int ntt = U.r.st[127];
        const int n16 = lane & 15;
        const int quad = lane >> 4;

        for (int bid2 = bid0; bid2 < ntt; bid2 += 1024) {
            __syncthreads();                        // protect XP/skj reuse
            if (t < 128) {
                int ntk = (U.r.sh[t] + 63) >> 6;
                int tb = U.r.st[t] - ntk;
                if (bid2 >= tb && bid2 < U.r.st[t]) { U.r.skj[0] = t; U.r.skj[1] = bid2 - tb; }
            }
            __syncthreads();
            const int k = U.r.skj[0];
            const int start = U.r.skj[1] << 6;
            const int cnt2 = U.r.sh[k];
            const int base2 = U.r.sv[k] - U.r.sh[k];

            // gather 64 xr rows -> frag-major LDS; 4 threads/row
            {
                int rs = t >> 2;
                int q = t & 3;
                int sidx = start + rs;
                if (sidx >= cnt2) sidx = cnt2 - 1;
                int n = bucket[base2 + sidx];
                const uint4* src = (const uint4*)(XRB + (unsigned)n * 128u + q * 32);
                uint4 a0 = src[0], a1 = src[1], a2 = src[2], a3 = src[3];
                unsigned db = (rs >> 4) * NST + q * 512 + (rs & 15) * 8;
                *(uint4*)&XP[db]       = a0;
                *(uint4*)&XP[db + 128] = a1;
                *(uint4*)&XP[db + 256] = a2;
                *(uint4*)&XP[db + 384] = a3;
            }
            __syncthreads();

            const unsigned short* wb = wbf + UW2K + (unsigned)k * 4096u;
            bf16x8 Bf[2][4];
            #pragma unroll
            for (int nf = 0; nf < 2; ++nf)
                #pragma unroll
                for (int kt = 0; kt < 4; ++kt)
                    Bf[nf][kt] = *(const bf16x8*)&wb[(nf * 16 + n16) * 128 + kt * 32 + quad * 8];

            const f32x4 vzero = {0.f, 0.f, 0.f, 0.f};
            f32x4 acc2[2];
            acc2[0] = vzero; acc2[1] = vzero;
            #pragma unroll
            for (int kt = 0; kt < 4; ++kt) {
                bf16x8 Af = *(const bf16x8*)&XP[wv * NST + kt * 512 + lane * 8];
                #pragma unroll
                for (int nf = 0; nf < 2; ++nf)
                    acc2[nf] = MFMA16(Af, Bf[nf][kt], acc2[nf], 0, 0, 0);
            }

            float b2a = cm2b[k * 32 + n16], b2b = cm2b[k * 32 + 16 + n16];
            float w3a = cm3w[k * 32 + n16], w3b = cm3w[k * 32 + 16 + n16];
            #pragma unroll
            for (int r = 0; r < 4; ++r) {
                float p = lrelu(acc2[0][r] + b2a) * w3a
                        + lrelu(acc2[1][r] + b2b) * w3b;
                p += __shfl_xor(p, 1);
                p += __shfl_xor(p, 2);
                p += __shfl_xor(p, 4);
                p += __shfl_xor(p, 8);
                if (n16 == 0)
                    red[wv * 16 + quad * 4 + r] = p;
            }
            __syncthreads();
            if (t < 64 && start + t < cnt2) {
                int n2 = bucket[base2 + start + t];
                out[n2] = ((float)k + red[t] + cm3b[k]) * (1.0f / 128.0f);
            }
        }
    }
}

extern "C" void kernel_launch(void* const* d_in, const int* in_sizes, int n_in,
                              void* d_out, int out_size, void* d_ws, size_t ws_size,
                              hipStream_t stream)
{
    (void)in_sizes; (void)n_in; (void)out_size; (void)ws_size;
    const float* x_in   = (const float*)d_in[0];
    const float* cl1_w  = (const float*)d_in[1];
    const float* cl1_b  = (const float*)d_in[2];
    const float* g1     = (const float*)d_in[3];
    const float* be1    = (const float*)d_in[4];
    const float* mu1    = (const float*)d_in[5];
    const float* va1    = (const float*)d_in[6];
    const float* cl2_w  = (const float*)d_in[7];
    const float* cl2_b  = (const float*)d_in[8];
    const float* cl3_w  = (const float*)d_in[9];
    const float* cl3_b  = (const float*)d_in[10];
    const float* reg1_w = (const float*)d_in[11];
    const float* reg1_b = (const float*)d_in[12];
    const float* gr     = (const float*)d_in[13];
    const float* ber    = (const float*)d_in[14];
    const float* mur    = (const float*)d_in[15];
    const float* var_   = (const float*)d_in[16];
    const float* cm2w   = (const float*)d_in[17];
    const float* cm2b   = (const float*)d_in[18];
    const float* cm3w   = (const float*)d_in[19];
    const float* cm3b   = (const float*)d_in[20];

    float* ws_f = (float*)d_ws;
    unsigned short* XRB = (unsigned short*)(ws_f + OFF_XR);
    unsigned short* wbf = (unsigned short*)(ws_f + OFF_BF16);
    int*   wsi    = (int*)(ws_f + OFF_INT);
    int*   inds   = wsi;
    int*   hist   = inds + 65536;          // 128*HPAD = 2048 ints (padded)
    int*   offb   = hist + 2048;           // (unused, layout kept)
    int*   cur    = offb + 128;            // 128*HPAD = 2048 ints (padded)
    int*   ntt    = cur + 2048;            // (unused, layout kept)
    int*   fixcnt = ntt + 4;
    int*   tiles  = fixcnt + 4;            // (unused, layout kept)
    int*   fixlist= tiles + 1536;
    int*   bucket = fixlist + 65536;
    int*   bar    = bucket + 65536;        // barrier state: 34 padded slots
    int*   bcnt   = bar;                   // 32 group counters (HPAD-padded)
    int*   broot  = bar + 32 * HPAD;
    int*   bgen   = bar + 33 * HPAD;
    float* out = (float*)d_out;
    float* out_mask_p = out + 65536;

    // zero barrier state (capture-legal; harness itself uses hipMemsetAsync)
    hipMemsetAsync(bar, 0, 34 * HPAD * sizeof(int), stream);

    hipLaunchKernelGGL(k_mega, dim3(1024), dim3(256), 0, stream,
                       x_in,
                       cl1_w, cl1_b, g1, be1, mu1, va1, cl2_w, cl2_b,
                       cl3_w, cl3_b, reg1_w, reg1_b, gr, ber, mur, var_,
                       cm2w, cm2b, cm3w, cm3b,
                       ws_f, wbf, XRB, out_mask_p,
                       inds, hist, cur, fixcnt, fixlist, bucket, out,
                       bcnt, broot, bgen);
}

// Round 8
// 293.247 us; speedup vs baseline: 2.1210x; 2.1210x over previous
//
#include <hip/hip_runtime.h>
#include <math.h>

// Problem constants
#define NPOS 65536   // B*H*W = 8*1*8192
#define NCH  128
#define DELTA 0.008f // argmax top-2 gap below which we recompute in exact fp32
#define HPAD 16      // ints per histogram bin slot (64 B = 1 cache line per bin)

// ws layout (float element offsets)
#define OFF_XR   0u                       // XRB bf16 [n][128] lives here
#define OFF_W1T  8388608u                 // fixup fp32 [cin][cout]
#define OFF_W2T  (OFF_W1T + 16384u)
#define OFF_W3T  (OFF_W2T + 16384u)
#define OFF_B1F  (OFF_W3T + 16384u)
#define OFF_BRF  (OFF_B1F + 128u)
#define OFF_B2F  (OFF_BRF + 128u)
#define OFF_B3F  (OFF_B2F + 128u)         // 132 (129 used)
#define OFF_BF16 (OFF_B3F + 132u)         // ushort region
#define OFF_INT  (OFF_BF16 + 329728u)     // int region (bf16 region = 659456 ushorts)

// ushort offsets inside bf16 region
#define UW1H 0u
#define UW1L 16384u
#define UWRH 32768u
#define UWRL 49152u
#define UW2H 65536u
#define UW2L 81920u
#define UW3H 98304u      // [144][128]; row128=mask, rows129..143=0
#define UW3L 116736u
#define UW2K 135168u     // cm2w bf16 transposed [k][out][ci] : 524288 -> end 659456

// frag-major LDS: [mg][kt][lane][8 ushorts], +32-ushort pad per mg
#define NST 2080         // 4*512 + 32

typedef short bf16x8 __attribute__((ext_vector_type(8)));
typedef float f32x4 __attribute__((ext_vector_type(4)));
#define MFMA16 __builtin_amdgcn_mfma_f32_16x16x32_bf16

__device__ __forceinline__ float lrelu(float v) { return v >= 0.0f ? v : 0.01f * v; }
__device__ __forceinline__ unsigned short f2bf(float f) {
    unsigned u = __float_as_uint(f);
    return (unsigned short)((u + 0x7fffu + ((u >> 16) & 1u)) >> 16);
}
__device__ __forceinline__ float bf2f(unsigned short h) {
    return __uint_as_float(((unsigned)h) << 16);
}
__device__ __forceinline__ unsigned long long pack4(unsigned short a, unsigned short b,
                                                    unsigned short c, unsigned short d) {
    return (unsigned long long)a | ((unsigned long long)b << 16)
         | ((unsigned long long)c << 32) | ((unsigned long long)d << 48);
}

// ---------------------------------------------------------------------------
// Manual grid barrier, R20. R19's version was correct but 110us/barrier:
// the ACQUIRE poll load emitted buffer_inv (FULL L2 invalidate) EVERY
// iteration x 1024 spinners -> stragglers' cached weights were wiped
// continuously (FETCH +8MB, all pipes <4% busy). Fix: fence exactly once
// per block per barrier —
//   arrival  = RELEASE fetch_add  (waitcnt + ONE buffer_wbl2 + atomic)
//   poll     = RELAXED load       (sc1 to coherence point, NO inv)
//   exit     = ONE acquire fence  (ONE buffer_inv) after gen observed
// Monotonic 2-level counters unchanged (proven in R19: absmax was exact).
// Co-residency: grid 1024 = 256 CU x 4 blocks, bounds(256,4), LDS 38,400B.
// ---------------------------------------------------------------------------
__device__ __forceinline__ void gridbar(int* cnt, int* root, int* gen, int bargen)
{
    __syncthreads();                 // block's lanes done with the phase
    if (threadIdx.x == 0) {
        int grp = (int)(blockIdx.x & 31u);
        // RELEASE arrival: flushes this block's writes (one wbl2), then adds.
        if (__hip_atomic_fetch_add(&cnt[grp * HPAD], 1, __ATOMIC_RELEASE,
                                   __HIP_MEMORY_SCOPE_AGENT) == 32 * bargen - 1) {
            if (__hip_atomic_fetch_add(root, 1, __ATOMIC_RELEASE,
                                       __HIP_MEMORY_SCOPE_AGENT) == 32 * bargen - 1) {
                __hip_atomic_store(gen, bargen, __ATOMIC_RELEASE,
                                   __HIP_MEMORY_SCOPE_AGENT);
            }
        }
        // RELAXED poll: no cache maintenance per iteration.
        while (__hip_atomic_load(gen, __ATOMIC_RELAXED,
                                 __HIP_MEMORY_SCOPE_AGENT) < bargen)
            __builtin_amdgcn_s_sleep(16);
        // ONE acquire fence: invalidate stale L1/L2 before reading others' data.
        __builtin_amdgcn_fence(__ATOMIC_ACQUIRE, "agent");
    }
    __syncthreads();
}

// ---------------------------------------------------------------------------
// R20: ONE kernel, PLAIN launch, cheap barriers. Phases are verbatim ports
// of the R17 kernels (bitwise-identical arithmetic):
//   P0 prep (blocks 0..255)  P1 fused (all 1024)  P2 fix (grid-stride)
//   P3 scatter (blocks 0..255)  P4 reg (grid-stride tiles)
// ---------------------------------------------------------------------------
__global__ __launch_bounds__(256, 4)
void k_mega(const float* __restrict__ X,
            const float* __restrict__ cl1_w, const float* __restrict__ cl1_b,
            const float* __restrict__ g1, const float* __restrict__ be1,
            const float* __restrict__ mu1, const float* __restrict__ va1,
            const float* __restrict__ cl2_w, const float* __restrict__ cl2_b,
            const float* __restrict__ cl3_w, const float* __restrict__ cl3_b,
            const float* __restrict__ reg1_w, const float* __restrict__ reg1_b,
            const float* __restrict__ gr, const float* __restrict__ ber,
            const float* __restrict__ mur, const float* __restrict__ var_,
            const float* __restrict__ cm2w, const float* __restrict__ cm2b,
            const float* __restrict__ cm3w, const float* __restrict__ cm3b,
            float* __restrict__ wsf, unsigned short* __restrict__ wbf,
            unsigned short* __restrict__ XRB, float* __restrict__ out_mask,
            int* __restrict__ inds, int* __restrict__ hist, int* __restrict__ cur,
            int* __restrict__ fixcnt, int* __restrict__ fixlist,
            int* __restrict__ bucket, float* __restrict__ out,
            int* __restrict__ bcnt, int* __restrict__ broot, int* __restrict__ bgen)
{
    __shared__ union __align__(16) SM {
        struct { float tl[32 * 132]; } prep;                       // 16,896 B
        struct {                                                   // 38,400 B
            unsigned short XBh[64 * 136];
            unsigned short XBl[64 * 136];
            float sm1[256]; float sm2[256]; int si1[256];
            int lh[128];
        } f;
        struct { float xw[4][128]; } x;                            //  2,048 B
        struct { int lh[128]; int gb[128]; int sv[128]; int sh[128]; } s;
        struct {                                                   // 18,440 B
            unsigned short XP[4 * NST];
            float red[64];
            int sh[128]; int sv[128]; int st[128]; int skj[2];
        } r;
    } U;

    const int t = threadIdx.x;
    const int bid0 = blockIdx.x;
    const int lane = t & 63;
    const int wv = __builtin_amdgcn_readfirstlane(t >> 6);

    // =================== Phase 0: prep ===================
    if (bid0 < 128) {
        if (t < 128) {
            const int cout = bid0;
            const int cin = t;
            const int row = cout * 128 + cin;
            float s1 = g1[cout] / sqrtf(va1[cout] + 1e-5f);
            float sr = gr[cout] / sqrtf(var_[cout] + 1e-5f);
            float w1 = cl1_w[row] * s1;
            float wr = reg1_w[row] * sr;
            float w2 = cl2_w[row];
            float w3 = cl3_w[row];
            wsf[OFF_W1T + cin * 128 + cout] = w1;
            wsf[OFF_W2T + cin * 128 + cout] = w2;
            wsf[OFF_W3T + cin * 128 + cout] = w3;
            unsigned short h;
            h = f2bf(w1); wbf[UW1H + row] = h; wbf[UW1L + row] = f2bf(w1 - bf2f(h));
            h = f2bf(wr); wbf[UWRH + row] = h; wbf[UWRL + row] = f2bf(wr - bf2f(h));
            h = f2bf(w2); wbf[UW2H + row] = h; wbf[UW2L + row] = f2bf(w2 - bf2f(h));
            h = f2bf(w3); wbf[UW3H + row] = h; wbf[UW3L + row] = f2bf(w3 - bf2f(h));
            if (bid0 < 16) {        // W3 rows 128..143: mask row then zeros
                float v = (bid0 == 0) ? cl3_w[128 * 128 + t] : 0.0f;
                int jj = (128 + bid0) * 128 + t;
                h = f2bf(v); wbf[UW3H + jj] = h; wbf[UW3L + jj] = f2bf(v - bf2f(h));
            }
            if (bid0 == 0) {
                float s1b = g1[t] / sqrtf(va1[t] + 1e-5f);
                float srb = gr[t] / sqrtf(var_[t] + 1e-5f);
                wsf[OFF_B1F + t] = cl1_b[t] * s1b + be1[t] - mu1[t] * s1b;
                wsf[OFF_BRF + t] = reg1_b[t] * srb + ber[t] - mur[t] * srb;
                wsf[OFF_B2F + t] = cl2_b[t];
                wsf[OFF_B3F + t] = cl3_b[t];
                hist[t * HPAD] = 0;
                cur[t * HPAD] = 0;
            }
            if (bid0 == 1 && t == 0) { wsf[OFF_B3F + 128] = cl3_b[128]; fixcnt[0] = 0; }
        }
    } else if (bid0 < 256) {                 // cm2w transpose, one k per block
        int k = bid0 - 128;
        if (t < 128) {
            #pragma unroll
            for (int i = 0; i < 32; ++i) {
                float v = cm2w[(unsigned)k * 4096u + i * 128 + t];
                int ci = i * 4 + (t >> 5), o = t & 31;
                U.prep.tl[o * 132 + ci] = v;
            }
        }
        __syncthreads();
        if (t < 128) {
            #pragma unroll
            for (int i = 0; i < 32; ++i)
                wbf[UW2K + (unsigned)k * 4096u + i * 128 + t] = f2bf(U.prep.tl[i * 132 + t]);
        }
    }
    gridbar(bcnt, broot, bgen, 1);

    // =================== Phase 1: fused MFMA pipeline ===================
    {
        auto& XBh = U.f.XBh;  auto& XBl = U.f.XBl;
        auto& sm1 = U.f.sm1;  auto& sm2 = U.f.sm2;  auto& si1 = U.f.si1;
        auto& lh  = U.f.lh;

        const int cl16 = lane & 15;
        const int q8 = (lane >> 4) * 8;
        const int q4 = (lane >> 4) * 4;
        const unsigned nt64 = bid0 * 64u;
        const unsigned base = nt64 + (nt64 >> 13) * 1040384u;   // b*1048576 + w0

        const unsigned short* W1H = wbf + UW1H; const unsigned short* W1L = wbf + UW1L;
        const unsigned short* WRH = wbf + UWRH; const unsigned short* WRL = wbf + UWRL;
        const unsigned short* W2H = wbf + UW2H; const unsigned short* W2L = wbf + UW2L;
        const unsigned short* W3H = wbf + UW3H; const unsigned short* W3L = wbf + UW3L;
        const float* b1f = wsf + OFF_B1F;
        const float* brf = wsf + OFF_BRF;
        const float* b2f = wsf + OFF_B2F;
        const float* b3f = wsf + OFF_B3F;

        const f32x4 vzero = {0.f, 0.f, 0.f, 0.f};

        // ---- stage x tile -> bf16 hi/lo planes [pos][cin] ----
        {
            const int pos = t & 63, cig = t >> 6;
            #pragma unroll
            for (int l = 0; l < 8; ++l) {
                int ci0 = cig * 32 + l * 4;
                float v0 = X[base + (unsigned)(ci0 + 0) * 8192u + pos];
                float v1 = X[base + (unsigned)(ci0 + 1) * 8192u + pos];
                float v2 = X[base + (unsigned)(ci0 + 2) * 8192u + pos];
                float v3 = X[base + (unsigned)(ci0 + 3) * 8192u + pos];
                unsigned short h0 = f2bf(v0), h1 = f2bf(v1), h2 = f2bf(v2), h3 = f2bf(v3);
                unsigned long long ph = pack4(h0, h1, h2, h3);
                unsigned long long pl = pack4(f2bf(v0 - bf2f(h0)), f2bf(v1 - bf2f(h1)),
                                              f2bf(v2 - bf2f(h2)), f2bf(v3 - bf2f(h3)));
                *(unsigned long long*)&XBh[pos * 136 + ci0] = ph;
                *(unsigned long long*)&XBl[pos * 136 + ci0] = pl;
            }
        }
        __syncthreads();

        f32x4 acc[2][4];

        // ---- P1a: xr = lrelu(WR x + br) ----
        #pragma unroll
        for (int m = 0; m < 2; ++m)
            #pragma unroll
            for (int n = 0; n < 4; ++n) acc[m][n] = vzero;
        #pragma unroll
        for (int kt = 0; kt < 4; ++kt) {
            bf16x8 Bh[4], Bl[4];
            #pragma unroll
            for (int n = 0; n < 4; ++n) {
                int bo = (n * 16 + cl16) * 136 + kt * 32 + q8;
                Bh[n] = *(const bf16x8*)&XBh[bo];
                Bl[n] = *(const bf16x8*)&XBl[bo];
            }
            #pragma unroll
            for (int m = 0; m < 2; ++m) {
                int ao = (wv * 32 + m * 16 + cl16) * 128 + kt * 32 + q8;
                bf16x8 arh = *(const bf16x8*)&WRH[ao], arl = *(const bf16x8*)&WRL[ao];
                #pragma unroll
                for (int n = 0; n < 4; ++n) {
                    acc[m][n] = MFMA16(arh, Bl[n], acc[m][n], 0, 0, 0);
                    acc[m][n] = MFMA16(arl, Bh[n], acc[m][n], 0, 0, 0);
                    acc[m][n] = MFMA16(arh, Bh[n], acc[m][n], 0, 0, 0);
                }
            }
        }
        // xr epilogue -> global XRB
        {
            #pragma unroll
            for (int m = 0; m < 2; ++m) {
                int cb = wv * 32 + m * 16 + q4;
                float br0 = brf[cb], br1 = brf[cb + 1], br2 = brf[cb + 2], br3 = brf[cb + 3];
                #pragma unroll
                for (int n = 0; n < 4; ++n) {
                    unsigned pb = (nt64 + n * 16 + cl16) * 128u + cb;
                    ushort4 xo;
                    xo.x = f2bf(lrelu(acc[m][n][0] + br0));
                    xo.y = f2bf(lrelu(acc[m][n][1] + br1));
                    xo.z = f2bf(lrelu(acc[m][n][2] + br2));
                    xo.w = f2bf(lrelu(acc[m][n][3] + br3));
                    *(ushort4*)&XRB[pb] = xo;
                }
            }
        }

        // ---- P1b: y1 = lrelu(W1 x + b1) ----
        #pragma unroll
        for (int m = 0; m < 2; ++m)
            #pragma unroll
            for (int n = 0; n < 4; ++n) acc[m][n] = vzero;
        #pragma unroll
        for (int kt = 0; kt < 4; ++kt) {
            bf16x8 Bh[4], Bl[4];
            #pragma unroll
            for (int n = 0; n < 4; ++n) {
                int bo = (n * 16 + cl16) * 136 + kt * 32 + q8;
                Bh[n] = *(const bf16x8*)&XBh[bo];
                Bl[n] = *(const bf16x8*)&XBl[bo];
            }
            #pragma unroll
            for (int m = 0; m < 2; ++m) {
                int ao = (wv * 32 + m * 16 + cl16) * 128 + kt * 32 + q8;
                bf16x8 a1h = *(const bf16x8*)&W1H[ao], a1l = *(const bf16x8*)&W1L[ao];
                #pragma unroll
                for (int n = 0; n < 4; ++n) {
                    acc[m][n] = MFMA16(a1h, Bl[n], acc[m][n], 0, 0, 0);
                    acc[m][n] = MFMA16(a1l, Bh[n], acc[m][n], 0, 0, 0);
                    acc[m][n] = MFMA16(a1h, Bh[n], acc[m][n], 0, 0, 0);
                }
            }
        }
        __syncthreads();
        // y1 epilogue -> XB planes
        {
            #pragma unroll
            for (int m = 0; m < 2; ++m) {
                int cb = wv * 32 + m * 16 + q4;
                float b0 = b1f[cb], b1 = b1f[cb + 1], b2 = b1f[cb + 2], b3 = b1f[cb + 3];
                #pragma unroll
                for (int n = 0; n < 4; ++n) {
                    float v0 = lrelu(acc[m][n][0] + b0), v1 = lrelu(acc[m][n][1] + b1);
                    float v2 = lrelu(acc[m][n][2] + b2), v3 = lrelu(acc[m][n][3] + b3);
                    unsigned short h0 = f2bf(v0), h1 = f2bf(v1), h2 = f2bf(v2), h3 = f2bf(v3);
                    unsigned long long ph = pack4(h0, h1, h2, h3);
                    unsigned long long pl = pack4(f2bf(v0 - bf2f(h0)), f2bf(v1 - bf2f(h1)),
                                                  f2bf(v2 - bf2f(h2)), f2bf(v3 - bf2f(h3)));
                    int idx = (n * 16 + cl16) * 136 + cb;
                    *(unsigned long long*)&XBh[idx] = ph;
                    *(unsigned long long*)&XBl[idx] = pl;
                }
            }
        }
        __syncthreads();

        // ---- P2: y2 = lrelu(W2 y1 + b2) ----
        #pragma unroll
        for (int m = 0; m < 2; ++m)
            #pragma unroll
            for (int n = 0; n < 4; ++n) acc[m][n] = vzero;
        #pragma unroll
        for (int kt = 0; kt < 4; ++kt) {
            bf16x8 Bh[4], Bl[4];
            #pragma unroll
            for (int n = 0; n < 4; ++n) {
                int bo = (n * 16 + cl16) * 136 + kt * 32 + q8;
                Bh[n] = *(const bf16x8*)&XBh[bo];
                Bl[n] = *(const bf16x8*)&XBl[bo];
            }
            #pragma unroll
            for (int m = 0; m < 2; ++m) {
                int ao = (wv * 32 + m * 16 + cl16) * 128 + kt * 32 + q8;
                bf16x8 ah = *(const bf16x8*)&W2H[ao], al = *(const bf16x8*)&W2L[ao];
                #pragma unroll
                for (int n = 0; n < 4; ++n) {
                    acc[m][n] = MFMA16(ah, Bl[n], acc[m][n], 0, 0, 0);
                    acc[m][n] = MFMA16(al, Bh[n], acc[m][n], 0, 0, 0);
                    acc[m][n] = MFMA16(ah, Bh[n], acc[m][n], 0, 0, 0);
                }
            }
        }
        __syncthreads();
        {
            #pragma unroll
            for (int m = 0; m < 2; ++m) {
                int cb = wv * 32 + m * 16 + q4;
                float b0 = b2f[cb], b1 = b2f[cb + 1], b2 = b2f[cb + 2], b3 = b2f[cb + 3];
                #pragma unroll
                for (int n = 0; n < 4; ++n) {
                    float v0 = lrelu(acc[m][n][0] + b0), v1 = lrelu(acc[m][n][1] + b1);
                    float v2 = lrelu(acc[m][n][2] + b2), v3 = lrelu(acc[m][n][3] + b3);
                    unsigned short h0 = f2bf(v0), h1 = f2bf(v1), h2 = f2bf(v2), h3 = f2bf(v3);
                    unsigned long long ph = pack4(h0, h1, h2, h3);
                    unsigned long long pl = pack4(f2bf(v0 - bf2f(h0)), f2bf(v1 - bf2f(h1)),
                                                  f2bf(v2 - bf2f(h2)), f2bf(v3 - bf2f(h3)));
                    int idx = (n * 16 + cl16) * 136 + cb;
                    *(unsigned long long*)&XBh[idx] = ph;
                    *(unsigned long long*)&XBl[idx] = pl;
                }
            }
        }
        __syncthreads();

        // ---- P3: logits + mask row ----
        f32x4 accM = vzero;
        #pragma unroll
        for (int m = 0; m < 2; ++m)
            #pragma unroll
            for (int n = 0; n < 4; ++n) acc[m][n] = vzero;
        #pragma unroll
        for (int kt = 0; kt < 4; ++kt) {
            bf16x8 Bh[4], Bl[4];
            #pragma unroll
            for (int n = 0; n < 4; ++n) {
                int bo = (n * 16 + cl16) * 136 + kt * 32 + q8;
                Bh[n] = *(const bf16x8*)&XBh[bo];
                Bl[n] = *(const bf16x8*)&XBl[bo];
            }
            #pragma unroll
            for (int m = 0; m < 2; ++m) {
                int ao = (wv * 32 + m * 16 + cl16) * 128 + kt * 32 + q8;
                bf16x8 ah = *(const bf16x8*)&W3H[ao], al = *(const bf16x8*)&W3L[ao];
                #pragma unroll
                for (int n = 0; n < 4; ++n) {
                    acc[m][n] = MFMA16(ah, Bl[n], acc[m][n], 0, 0, 0);
                    acc[m][n] = MFMA16(al, Bh[n], acc[m][n], 0, 0, 0);
                    acc[m][n] = MFMA16(ah, Bh[n], acc[m][n], 0, 0, 0);
                }
            }
            {   // mask row; B-frag re-read from LDS at wave-uniform runtime addr
                int boM = (wv * 16 + cl16) * 136 + kt * 32 + q8;
                bf16x8 BhM = *(const bf16x8*)&XBh[boM];
                bf16x8 BlM = *(const bf16x8*)&XBl[boM];
                int ao = (128 + cl16) * 128 + kt * 32 + q8;
                bf16x8 ah = *(const bf16x8*)&W3H[ao], al = *(const bf16x8*)&W3L[ao];
                accM = MFMA16(ah, BlM, accM, 0, 0, 0);
                accM = MFMA16(al, BhM, accM, 0, 0, 0);
                accM = MFMA16(ah, BhM, accM, 0, 0, 0);
            }
        }

        // per-lane top-2, reduce, provisional hist, fix flags
        {
            float bb[2][4];
            #pragma unroll
            for (int m = 0; m < 2; ++m) {
                int cb = wv * 32 + m * 16 + q4;
                bb[m][0] = b3f[cb]; bb[m][1] = b3f[cb + 1];
                bb[m][2] = b3f[cb + 2]; bb[m][3] = b3f[cb + 3];
            }
            float m1[4], m2[4]; int i1[4];
            #pragma unroll
            for (int n = 0; n < 4; ++n) {
                m1[n] = -1e30f; m2[n] = -1e30f; i1[n] = 0;
                #pragma unroll
                for (int m = 0; m < 2; ++m) {
                    int cb = wv * 32 + m * 16 + q4;
                    #pragma unroll
                    for (int r = 0; r < 4; ++r) {
                        float v = acc[m][n][r] + bb[m][r];
                        if (v > m1[n]) { m2[n] = m1[n]; m1[n] = v; i1[n] = cb + r; }
                        else if (v > m2[n]) m2[n] = v;
                    }
                }
            }
            #pragma unroll
            for (int off = 16; off <= 32; off <<= 1) {
                #pragma unroll
                for (int n = 0; n < 4; ++n) {
                    float om1 = __shfl_xor(m1[n], off);
                    float om2 = __shfl_xor(m2[n], off);
                    int   oi1 = __shfl_xor(i1[n], off);
                    if (om1 > m1[n] || (om1 == m1[n] && oi1 < i1[n])) {
                        m2[n] = fmaxf(m1[n], om2); m1[n] = om1; i1[n] = oi1;
                    } else {
                        m2[n] = fmaxf(m2[n], om1);
                    }
                }
            }
            if ((lane >> 4) == 0) {
                #pragma unroll
                for (int n = 0; n < 4; ++n) {
                    sm1[wv * 64 + n * 16 + cl16] = m1[n];
                    sm2[wv * 64 + n * 16 + cl16] = m2[n];
                    si1[wv * 64 + n * 16 + cl16] = i1[n];
                }
            }
        }
        if ((lane >> 4) == 0) {
            float mb = b3f[128];
            out_mask[nt64 + wv * 16 + cl16] = lrelu(accM[0] + mb);
        }
        if (t < 128) lh[t] = 0;
        __syncthreads();
        if (t < 64) {
            float m1 = sm1[t], m2 = sm2[t];
            int i1 = si1[t];
            #pragma unroll
            for (int w = 1; w < 4; ++w) {
                float v1 = sm1[w * 64 + t];
                float v2 = sm2[w * 64 + t];
                int   vi = si1[w * 64 + t];
                if (v1 > m1) { m2 = fmaxf(m1, v2); m1 = v1; i1 = vi; }
                else         { m2 = fmaxf(m2, v1); }
            }
            int n = nt64 + t;
            inds[n] = i1;
            atomicAdd(&lh[i1], 1);
            if (m1 - m2 < DELTA) {
                int slot = atomicAdd(fixcnt, 1);
                fixlist[slot] = n;
            }
        }
        __syncthreads();
        if (t < 128 && lh[t] > 0) atomicAdd(&hist[t * HPAD], lh[t]);
    }
    gridbar(bcnt, broot, bgen, 2);

    // =================== Phase 2: exact-fp32 fixup (grid-stride) ===========
    {
        const int cnt = fixcnt[0];
        const float* W1T = wsf + OFF_W1T;
        const float* W2T = wsf + OFF_W2T;
        const float* W3T = wsf + OFF_W3T;
        const float* b1f = wsf + OFF_B1F;
        const float* b2f = wsf + OFF_B2F;
        const float* b3f = wsf + OFF_B3F;

        for (int idx = bid0 * 4 + wv; idx < cnt; idx += 4096) {
            int n = fixlist[idx];
            int oldid = inds[n];
            const float* xb = X + (unsigned)(n >> 13) * 1048576u + (unsigned)(n & 8191);
            float x0 = xb[(unsigned)lane * 8192u];
            float x1 = xb[(unsigned)(64 + lane) * 8192u];
            float a0, a1;

            U.x.xw[wv][lane] = x0; U.x.xw[wv][64 + lane] = x1;
            a0 = 0.f; a1 = 0.f;
            #pragma unroll 16
            for (int ci = 0; ci < 128; ++ci) {
                float xv = U.x.xw[wv][ci];
                const float* wr = W1T + ci * 128;
                a0 = fmaf(wr[lane], xv, a0);
                a1 = fmaf(wr[64 + lane], xv, a1);
            }
            x0 = lrelu(a0 + b1f[lane]); x1 = lrelu(a1 + b1f[64 + lane]);

            U.x.xw[wv][lane] = x0; U.x.xw[wv][64 + lane] = x1;
            a0 = 0.f; a1 = 0.f;
            #pragma unroll 16
            for (int ci = 0; ci < 128; ++ci) {
                float xv = U.x.xw[wv][ci];
                const float* wr = W2T + ci * 128;
                a0 = fmaf(wr[lane], xv, a0);
                a1 = fmaf(wr[64 + lane], xv, a1);
            }
            x0 = lrelu(a0 + b2f[lane]); x1 = lrelu(a1 + b2f[64 + lane]);

            U.x.xw[wv][lane] = x0; U.x.xw[wv][64 + lane] = x1;
            a0 = 0.f; a1 = 0.f;
            #pragma unroll 16
            for (int ci = 0; ci < 128; ++ci) {
                float xv = U.x.xw[wv][ci];
                const float* wr = W3T + ci * 128;
                a0 = fmaf(wr[lane], xv, a0);
                a1 = fmaf(wr[64 + lane], xv, a1);
            }
            float L0 = a0 + b3f[lane], L1 = a1 + b3f[64 + lane];
            float v; int id;
            if (L0 >= L1) { v = L0; id = lane; } else { v = L1; id = 64 + lane; }
            #pragma unroll
            for (int off = 1; off < 64; off <<= 1) {
                float ov = __shfl_xor(v, off);
                int   oi = __shfl_xor(id, off);
                if (ov > v || (ov == v && oi < id)) { v = ov; id = oi; }
            }
            if (lane == 0 && id != oldid) {
                inds[n] = id;
                atomicSub(&hist[oldid * HPAD], 1);
                atomicAdd(&hist[id * HPAD], 1);
            }
        }
    }
    gridbar(bcnt, broot, bgen, 3);

    // =================== Phase 3: scatter (blocks 0..255) ==================
    if (bid0 < 256) {
        if (t < 128) { int h = hist[t * HPAD]; U.s.sh[t] = h; U.s.sv[t] = h; U.s.lh[t] = 0; }
        __syncthreads();
        for (int d = 1; d < 128; d <<= 1) {
            int a = (t < 128 && t >= d) ? U.s.sv[t - d] : 0;
            __syncthreads();
            if (t < 128) U.s.sv[t] += a;
            __syncthreads();
        }
        int n = bid0 * 256 + t;
        int id = inds[n];
        int r = atomicAdd(&U.s.lh[id], 1);
        __syncthreads();
        if (t < 128 && U.s.lh[t] > 0)
            U.s.gb[t] = (U.s.sv[t] - U.s.sh[t]) + atomicAdd(&cur[t * HPAD], U.s.lh[t]);
        __syncthreads();
        bucket[U.s.gb[id] + r] = n;
    }
    gridbar(bcnt, broot, bgen, 4);

    // =================== Phase 4: bucketed reg MLP (grid-stride tiles) =====
    {
        auto& XP = U.r.XP;  auto& red = U.r.red;
        if (t < 128) {
            int h = hist[t * HPAD];
            U.r.sh[t] = h; U.r.sv[t] = h; U.r.st[t] = (h + 63) >> 6;
        }
        __syncthreads();
        for (int d = 1; d < 128; d <<= 1) {
            int a = (t < 128 && t >= d) ? U.r.sv[t - d] : 0;
            int b = (t < 128 && t >= d) ? U.r.st[t - d] : 0;
            __syncthreads();
            if (t < 128) { U.r.sv[t] += a; U.r.st[t] += b; }
            __syncthreads();
        }
        const int ntt = U.r.st[127];
        const int n16 = lane & 15;
        const int quad = lane >> 4;

        for (int bid2 = bid0; bid2 < ntt; bid2 += 1024) {
            __syncthreads();                        // protect XP/skj reuse
            if (t < 128) {
                int ntk = (U.r.sh[t] + 63) >> 6;
                int tb = U.r.st[t] - ntk;
                if (bid2 >= tb && bid2 < U.r.st[t]) { U.r.skj[0] = t; U.r.skj[1] = bid2 - tb; }
            }
            __syncthreads();
            const int k = U.r.skj[0];
            const int start = U.r.skj[1] << 6;
            const int cnt2 = U.r.sh[k];
            const int base2 = U.r.sv[k] - U.r.sh[k];

            // gather 64 xr rows -> frag-major LDS; 4 threads/row
            {
                int rs = t >> 2;
                int q = t & 3;
                int sidx = start + rs;
                if (sidx >= cnt2) sidx = cnt2 - 1;
                int n = bucket[base2 + sidx];
                const uint4* src = (const uint4*)(XRB + (unsigned)n * 128u + q * 32);
                uint4 a0 = src[0], a1 = src[1], a2 = src[2], a3 = src[3];
                unsigned db = (rs >> 4) * NST + q * 512 + (rs & 15) * 8;
                *(uint4*)&XP[db]       = a0;
                *(uint4*)&XP[db + 128] = a1;
                *(uint4*)&XP[db + 256] = a2;
                *(uint4*)&XP[db + 384] = a3;
            }
            __syncthreads();

            const unsigned short* wb = wbf + UW2K + (unsigned)k * 4096u;
            bf16x8 Bf[2][4];
            #pragma unroll
            for (int nf = 0; nf < 2; ++nf)
                #pragma unroll
                for (int kt = 0; kt < 4; ++kt)
                    Bf[nf][kt] = *(const bf16x8*)&wb[(nf * 16 + n16) * 128 + kt * 32 + quad * 8];

            const f32x4 vzero = {0.f, 0.f, 0.f, 0.f};
            f32x4 acc2[2];
            acc2[0] = vzero; acc2[1] = vzero;
            #pragma unroll
            for (int kt = 0; kt < 4; ++kt) {
                bf16x8 Af = *(const bf16x8*)&XP[wv * NST + kt * 512 + lane * 8];
                #pragma unroll
                for (int nf = 0; nf < 2; ++nf)
                    acc2[nf] = MFMA16(Af, Bf[nf][kt], acc2[nf], 0, 0, 0);
            }

            float b2a = cm2b[k * 32 + n16], b2b = cm2b[k * 32 + 16 + n16];
            float w3a = cm3w[k * 32 + n16], w3b = cm3w[k * 32 + 16 + n16];
            #pragma unroll
            for (int r = 0; r < 4; ++r) {
                float p = lrelu(acc2[0][r] + b2a) * w3a
                        + lrelu(acc2[1][r] + b2b) * w3b;
                p += __shfl_xor(p, 1);
                p += __shfl_xor(p, 2);
                p += __shfl_xor(p, 4);
                p += __shfl_xor(p, 8);
                if (n16 == 0)
                    red[wv * 16 + quad * 4 + r] = p;
            }
            __syncthreads();
            if (t < 64 && start + t < cnt2) {
                int n2 = bucket[base2 + start + t];
                out[n2] = ((float)k + red[t] + cm3b[k]) * (1.0f / 128.0f);
            }
        }
    }
}

extern "C" void kernel_launch(void* const* d_in, const int* in_sizes, int n_in,
                              void* d_out, int out_size, void* d_ws, size_t ws_size,
                              hipStream_t stream)
{
    (void)in_sizes; (void)n_in; (void)out_size; (void)ws_size;
    const float* x_in   = (const float*)d_in[0];
    const float* cl1_w  = (const float*)d_in[1];
    const float* cl1_b  = (const float*)d_in[2];
    const float* g1     = (const float*)d_in[3];
    const float* be1    = (const float*)d_in[4];
    const float* mu1    = (const float*)d_in[5];
    const float* va1    = (const float*)d_in[6];
    const float* cl2_w  = (const float*)d_in[7];
    const float* cl2_b  = (const float*)d_in[8];
    const float* cl3_w  = (const float*)d_in[9];
    const float* cl3_b  = (const float*)d_in[10];
    const float* reg1_w = (const float*)d_in[11];
    const float* reg1_b = (const float*)d_in[12];
    const float* gr     = (const float*)d_in[13];
    const float* ber    = (const float*)d_in[14];
    const float* mur    = (const float*)d_in[15];
    const float* var_   = (const float*)d_in[16];
    const float* cm2w   = (const float*)d_in[17];
    const float* cm2b   = (const float*)d_in[18];
    const float* cm3w   = (const float*)d_in[19];
    const float* cm3b   = (const float*)d_in[20];

    float* ws_f = (float*)d_ws;
    unsigned short* XRB = (unsigned short*)(ws_f + OFF_XR);
    unsigned short* wbf = (unsigned short*)(ws_f + OFF_BF16);
    int*   wsi    = (int*)(ws_f + OFF_INT);
    int*   inds   = wsi;
    int*   hist   = inds + 65536;          // 128*HPAD = 2048 ints (padded)
    int*   offb   = hist + 2048;           // (unused, layout kept)
    int*   cur    = offb + 128;            // 128*HPAD = 2048 ints (padded)
    int*   ntt    = cur + 2048;            // (unused, layout kept)
    int*   fixcnt = ntt + 4;
    int*   tiles  = fixcnt + 4;            // (unused, layout kept)
    int*   fixlist= tiles + 1536;
    int*   bucket = fixlist + 65536;
    int*   bar    = bucket + 65536;        // barrier state: 34 padded slots
    int*   bcnt   = bar;                   // 32 group counters (HPAD-padded)
    int*   broot  = bar + 32 * HPAD;
    int*   bgen   = bar + 33 * HPAD;
    float* out = (float*)d_out;
    float* out_mask_p = out + 65536;

    // zero barrier state (capture-legal; harness itself uses hipMemsetAsync)
    hipMemsetAsync(bar, 0, 34 * HPAD * sizeof(int), stream);

    hipLaunchKernelGGL(k_mega, dim3(1024), dim3(256), 0, stream,
                       x_in,
                       cl1_w, cl1_b, g1, be1, mu1, va1, cl2_w, cl2_b,
                       cl3_w, cl3_b, reg1_w, reg1_b, gr, ber, mur, var_,
                       cm2w, cm2b, cm3w, cm3b,
                       ws_f, wbf, XRB, out_mask_p,
                       inds, hist, cur, fixcnt, fixlist, bucket, out,
                       bcnt, broot, bgen);
}